// Round 12
// baseline (191.498 us; speedup 1.0000x reference)
//
#include <hip/hip_runtime.h>
#include <stdint.h>
#include <stddef.h>

#define BB 16384
#define CC 500
#define DD 512
#define PADC 512
#define LMARGIN 1.0f
#define EPSQ 1e-12f
#define NKC 16   // K-chunks of 32
#define ROWS 32  // rows per block

typedef __attribute__((ext_vector_type(8))) _Float16 f16x8;
typedef __attribute__((ext_vector_type(4))) float f32x4;

#define GLOBAL_AS __attribute__((address_space(1)))
#define LDS_AS __attribute__((address_space(3)))

__device__ __forceinline__ void ld_lds16(const void* g, void* l) {
  __builtin_amdgcn_global_load_lds((const GLOBAL_AS void*)g, (LDS_AS void*)l, 16, 0, 0);
}

// ---- prepP: protos fp32 -> protoT f16 in FRAGMENT-LINEAR layout + p2 ----
// unit (cg, kc) at byte (cg*16 + kc)*1024; lane l's 16 B inside a unit =
// B[col = cg*16 + (l&15)][k = kc*32 + (l>>4)*8 .. +7].
__global__ void prepP_kernel(const float* __restrict__ protos,
                             unsigned short* __restrict__ protoT,
                             float* __restrict__ p2,
                             float* __restrict__ out) {
  __shared__ float s_arr[16][17];
  const int cg = blockIdx.x;   // 0..31
  const int t = threadIdx.x;   // 0..255
  const int colin = t & 15;
  const int jb = t >> 4;       // 0..15
  const int col = cg * 16 + colin;
  if (cg == 0 && t == 0) out[0] = 0.f;
  float s = 0.f;
#pragma unroll
  for (int u = 0; u < 4; ++u) {
    const int j8 = jb + u * 16;          // 0..63: 8-float k-unit
    const int kc = j8 >> 2, quad = j8 & 3;
    f32x4 a0 = {0.f, 0.f, 0.f, 0.f}, a1 = a0;
    if (col < CC) {
      const float* src = protos + (size_t)col * DD + j8 * 8;
      a0 = *(const f32x4*)src;
      a1 = *(const f32x4*)(src + 4);
    }
    f16x8 h;
#pragma unroll
    for (int uu = 0; uu < 4; ++uu) {
      h[uu] = (_Float16)a0[uu];
      h[uu + 4] = (_Float16)a1[uu];
      s = fmaf(a0[uu], a0[uu], s);
      s = fmaf(a1[uu], a1[uu], s);
    }
    *(f16x8*)(protoT + (size_t)(cg * 16 + kc) * 512 + (quad * 16 + colin) * 8) = h;
  }
  s_arr[colin][jb] = s;
  __syncthreads();
  if (t < 16) {
    float acc = 0.f;
#pragma unroll
    for (int i = 0; i < 16; ++i) acc += s_arr[t][i];
    p2[cg * 16 + t] = acc;
  }
}

// ---- main: 512 blocks x 576 threads = 8 COMPUTE waves + 1 PRODUCER wave.
// Block = 32 rows x 512 cols; compute wave w = all 32 rows x 64-col octant,
// acc 2x4 of 16x16x32. Producer wave DMA-streams fp32 A in 4 quarter-batches
// (16 KB) into a 3-slot LDS ring, signalling via LDS flags after
// __threadfence_block() (waits ONLY the producer's vmcnt). Consumers spin on
// the flag, keep a private B ring (fragment-linear global->VGPR, depth-2;
// their vmcnt tracks only B -> fine-grained, never drained), convert fp32->
// f16 at fragment read (f2 folded in). Slot-0 reuse (quarter 3) gated by a
// consumer done-counter. NO barriers anywhere in the K-phase. ----
__launch_bounds__(576, 4)
__global__ void main_kernel(const float* __restrict__ feat,
                            const unsigned short* __restrict__ protoT,
                            const float* __restrict__ p2,
                            const int* __restrict__ labels,
                            float* __restrict__ outp) {
  __shared__ __align__(16) unsigned char Aring[3][16384];  // 48 KB fp32 A ring
  __shared__ float redM[ROWS * 8], redP[ROWS * 8];         // 2 KB
  __shared__ float f2l[ROWS];
  __shared__ int flagA[4];
  __shared__ int done0;

  const int tid = threadIdx.x;
  const int w = tid >> 6;        // 0..7 compute, 8 producer
  const int lane = tid & 63;
  const int r0 = blockIdx.x * ROWS;

  if (tid == 0) {
    flagA[0] = flagA[1] = flagA[2] = flagA[3] = 0;
    done0 = 0;
  }
  __syncthreads();  // barrier 1: flags initialized (before any DMA issues)

  if (w == 8) {
    // ================= PRODUCER WAVE =================
    // instr (kcl, p): rows p*8 + (lane>>3), global chunk (lane&7)^(row&7)
    // stored at slot byte kcl*4096 + p*1024 + lane*16 (swizzle for readers).
    const int l3 = lane >> 3, j8 = lane & 7;
    const float* aBase = feat + (size_t)(r0 + l3) * DD + ((j8 ^ l3) << 2);
#pragma unroll 1
    for (int q = 0; q < 4; ++q) {
      if (q == 3) {  // slot 0 reuse: wait until all consumers finished q0
        volatile int* vd = &done0;
        while (*vd < 8) __builtin_amdgcn_s_sleep(8);
      }
      char* slot = (char*)&Aring[q % 3][0] + lane * 16;
#pragma unroll
      for (int kcl = 0; kcl < 4; ++kcl)
#pragma unroll
        for (int p = 0; p < 4; ++p)
          ld_lds16(aBase + (size_t)(p * 8) * DD + (q * 4 + kcl) * 32,
                   slot + kcl * 4096 + p * 1024);
      __threadfence_block();           // drains producer vmcnt -> data in LDS
      ((volatile int*)flagA)[q] = 1;   // publish
    }
  } else {
    // ================= COMPUTE WAVES =================
    const int lane16 = lane & 15;
    const int quad = lane >> 4;
    const int r7 = lane16 & 7;
    const int c0 = ((quad * 2) ^ r7) * 16;       // swizzled slot of chunk 2q
    const int c1 = ((quad * 2 + 1) ^ r7) * 16;   // and 2q+1

    const char* bptr[4];
#pragma unroll
    for (int nt = 0; nt < 4; ++nt)
      bptr[nt] = (const char*)protoT + (size_t)(w * 64 + nt * 16) * 1024 +
                 lane * 16;
    f16x8 bfr[3][4];
#pragma unroll
    for (int nt = 0; nt < 4; ++nt) {
      bfr[0][nt] = *(const f16x8*)(bptr[nt]);
      bfr[1][nt] = *(const f16x8*)(bptr[nt] + 1024);
    }

    f32x4 acc[2][4];
#pragma unroll
    for (int mt = 0; mt < 2; ++mt)
#pragma unroll
      for (int nt = 0; nt < 4; ++nt) acc[mt][nt] = (f32x4){0.f, 0.f, 0.f, 0.f};
    float f2part[2] = {0.f, 0.f};

#pragma unroll 1
    for (int q = 0; q < 4; ++q) {
      {  // wait for this quarter's A (broadcast LDS read, all lanes uniform)
        volatile int* vf = &flagA[q];
        while (*vf == 0) __builtin_amdgcn_s_sleep(2);
      }
      const unsigned char* slot = &Aring[q % 3][0];
#pragma unroll
      for (int j = 0; j < 4; ++j) {
        const int kc = q * 4 + j;
        if (kc + 2 < NKC) {
#pragma unroll
          for (int nt = 0; nt < 4; ++nt)
            bfr[(kc + 2) % 3][nt] =
                *(const f16x8*)(bptr[nt] + (size_t)(kc + 2) * 1024);
        }
        f16x8 af[2];
#pragma unroll
        for (int mt = 0; mt < 2; ++mt) {
          const unsigned char* ab = slot + j * 4096 + (mt * 16 + lane16) * 128;
          f32x4 x0 = *(const f32x4*)(ab + c0);
          f32x4 x1 = *(const f32x4*)(ab + c1);
          f16x8 a;
#pragma unroll
          for (int u = 0; u < 4; ++u) {
            a[u] = (_Float16)x0[u];
            a[u + 4] = (_Float16)x1[u];
            f2part[mt] = fmaf(x0[u], x0[u], f2part[mt]);
            f2part[mt] = fmaf(x1[u], x1[u], f2part[mt]);
          }
          af[mt] = a;
        }
#pragma unroll
        for (int mt = 0; mt < 2; ++mt)
#pragma unroll
          for (int nt = 0; nt < 4; ++nt)
            acc[mt][nt] = __builtin_amdgcn_mfma_f32_16x16x32_f16(
                af[mt], bfr[kc % 3][nt], acc[mt][nt], 0, 0, 0);
      }
      if (q == 0 && lane == 0) atomicAdd(&done0, 1);  // release slot 0
    }

    // f2: each wave saw every A element once; reduce over the 4 quads
#pragma unroll
    for (int mt = 0; mt < 2; ++mt) {
      f2part[mt] += __shfl_xor(f2part[mt], 16, 64);
      f2part[mt] += __shfl_xor(f2part[mt], 32, 64);
    }
    if (w == 0 && quad == 0) {
      f2l[lane16] = f2part[0];
      f2l[16 + lane16] = f2part[1];
    }

    // epilogue: q = p2 - 2*dot; masked min/pos over my 64 cols
    float p2v[4];
#pragma unroll
    for (int nt = 0; nt < 4; ++nt) p2v[nt] = p2[w * 64 + nt * 16 + lane16];
#pragma unroll
    for (int mt = 0; mt < 2; ++mt) {
#pragma unroll
      for (int i = 0; i < 4; ++i) {
        const int row = mt * 16 + quad * 4 + i;
        const int lb = labels[r0 + row];  // wave-uniform broadcast
        float qm = 1e30f, qp = -1e30f;
#pragma unroll
        for (int nt = 0; nt < 4; ++nt) {
          const int col = w * 64 + nt * 16 + lane16;
          float qv = p2v[nt] - 2.f * acc[mt][nt][i];
          bool isPos = (col == lb);
          qp = fmaxf(qp, isPos ? qv : -1e30f);
          qm = fminf(qm, (!isPos && col < CC) ? qv : 1e30f);
        }
#pragma unroll
        for (int d = 1; d < 16; d <<= 1) {
          qm = fminf(qm, __shfl_xor(qm, d, 64));
          qp = fmaxf(qp, __shfl_xor(qp, d, 64));
        }
        if (lane16 == 0) {
          redM[row * 8 + w] = qm;
          redP[row * 8 + w] = qp;
        }
      }
    }
  }

  __syncthreads();  // barrier 2: partials + f2l visible (producer joins here)

  // combine 8 octants per row, sqrt + hinge, block sum, one atomic
  if (tid < ROWS) {
    float qm = 1e30f, qp = -1e30f;
#pragma unroll
    for (int j = 0; j < 8; ++j) {
      qm = fminf(qm, redM[tid * 8 + j]);
      qp = fmaxf(qp, redP[tid * 8 + j]);
    }
    float f2 = f2l[tid];
    float dn = sqrtf(fmaxf(f2 + qm, EPSQ));
    float dp = sqrtf(fmaxf(f2 + qp, EPSQ));
    float term = fmaxf(dp - dn + LMARGIN, 0.f);
#pragma unroll
    for (int d = 1; d < 32; d <<= 1) term += __shfl_xor(term, d, 64);
    if (tid == 0) atomicAdd(outp, term * (1.0f / BB));
  }
}

extern "C" void kernel_launch(void* const* d_in, const int* in_sizes, int n_in,
                              void* d_out, int out_size, void* d_ws, size_t ws_size,
                              hipStream_t stream) {
  const float* feat = (const float*)d_in[0];
  const float* protos = (const float*)d_in[1];
  const int* labels = (const int*)d_in[2];
  float* out = (float*)d_out;

  char* ws = (char*)d_ws;
  unsigned short* protoT = (unsigned short*)(ws);   // 512 KB fragment-linear B
  float* p2 = (float*)(ws + (512 << 10));           // 2 KB

  prepP_kernel<<<32, 256, 0, stream>>>(protos, protoT, p2, out);
  main_kernel<<<BB / ROWS, 576, 0, stream>>>(feat, protoT, p2, labels, out);
}

// Round 13
// 93.223 us; speedup vs baseline: 2.0542x; 2.0542x over previous
//
#include <hip/hip_runtime.h>
#include <stdint.h>
#include <stddef.h>

#define BB 16384
#define CC 500
#define DD 512
#define PADC 512
#define LMARGIN 1.0f
#define EPSQ 1e-12f
#define NK 16  // K-chunks of 32

typedef __attribute__((ext_vector_type(8))) _Float16 f16x8;
typedef __attribute__((ext_vector_type(4))) _Float16 f16x4;
typedef __attribute__((ext_vector_type(4))) float f32x4;

// ---- prepP: protos fp32 -> protoT f16 in FRAGMENT-LINEAR layout + p2 ----
// unit (cg, kc) at byte (cg*16 + kc)*1024; lane l's 16 B inside a unit =
// B[col = cg*16 + (l&15)][k = kc*32 + (l>>4)*8 .. +7]. A wave's B-fragment
// load is then one contiguous 1KB dwordx4.
__global__ void prepP_kernel(const float* __restrict__ protos,
                             unsigned short* __restrict__ protoT,
                             float* __restrict__ p2,
                             float* __restrict__ out) {
  __shared__ float s_arr[16][17];
  const int cg = blockIdx.x;   // 0..31
  const int t = threadIdx.x;   // 0..255
  const int colin = t & 15;
  const int jb = t >> 4;       // 0..15
  const int col = cg * 16 + colin;
  if (cg == 0 && t == 0) out[0] = 0.f;
  float s = 0.f;
#pragma unroll
  for (int u = 0; u < 4; ++u) {
    const int j8 = jb + u * 16;          // 0..63: 8-float k-unit
    const int kc = j8 >> 2, quad = j8 & 3;
    f32x4 a0 = {0.f, 0.f, 0.f, 0.f}, a1 = a0;
    if (col < CC) {
      const float* src = protos + (size_t)col * DD + j8 * 8;
      a0 = *(const f32x4*)src;
      a1 = *(const f32x4*)(src + 4);
    }
    f16x8 h;
#pragma unroll
    for (int uu = 0; uu < 4; ++uu) {
      h[uu] = (_Float16)a0[uu];
      h[uu + 4] = (_Float16)a1[uu];
      s = fmaf(a0[uu], a0[uu], s);
      s = fmaf(a1[uu], a1[uu], s);
    }
    *(f16x8*)(protoT + (size_t)(cg * 16 + kc) * 512 + (quad * 16 + colin) * 8) = h;
  }
  s_arr[colin][jb] = s;
  __syncthreads();
  if (t < 16) {
    float acc = 0.f;
#pragma unroll
    for (int i = 0; i < 16; ++i) acc += s_arr[t][i];
    p2[cg * 16 + t] = acc;
  }
}

// ---- main (R8 structure, best-measured 93.1 us, + consistent kc rotation):
// 256 blocks x 512 threads (8 waves); block = 64 rows x 512 cols; wave = all
// 64 rows x 64-col octant; acc 4x4 of 16x16x32.
// A: full 64x512 tile fp32->f16 into XOR-swizzled LDS in the PROLOGUE (only
// HBM phase). K-loop BARRIER-FREE: A from LDS (conflict-free), B fragment-
// linear global->VGPR (contiguous 1KB loads, ring-3/depth-2, L2-resident),
// both streams rotated by rot=(bid>>3)&15 so the 32 CUs of an XCD spread
// over protoT's 16 kc pages instead of bursting on page 0 together.
// Exactly 2 __syncthreads. Hinge completes in-block. ----
__launch_bounds__(512, 2)
__global__ void main_kernel(const float* __restrict__ feat,
                            const unsigned short* __restrict__ protoT,
                            const float* __restrict__ p2,
                            const int* __restrict__ labels,
                            float* __restrict__ out) {
  __shared__ __align__(16) unsigned char Afull[NK * 4096];  // 64 KB
  __shared__ float p2l[PADC];
  __shared__ float f2l[64];
  __shared__ int labl[64];
  __shared__ float redM[64 * 8], redP[64 * 8];

  const int tid = threadIdx.x;
  const int w = tid >> 6;
  const int lane = tid & 63;
  const int lane16 = lane & 15;
  const int quad = lane >> 4;
  const int r0 = blockIdx.x * 64;
  const int rot = (blockIdx.x >> 3) & 15;  // same stagger for A pages + B units

  // ---- B pointers: unit (cg = w*4+nt, kc) at byte (cg*16+kc)*1024 ----
  const char* bptr[4];
#pragma unroll
  for (int nt = 0; nt < 4; ++nt)
    bptr[nt] = (const char*)protoT + (size_t)(w * 64 + nt * 16) * 1024 + lane * 16;

  // issue B(kr(0)), B(kr(1)) early (L2; retire during the A prologue)
  f16x8 bfr[3][4];
#pragma unroll
  for (int nt = 0; nt < 4; ++nt) {
    bfr[0][nt] = *(const f16x8*)(bptr[nt] + (size_t)rot * 1024);
    bfr[1][nt] = *(const f16x8*)(bptr[nt] + (size_t)((rot + 1) & 15) * 1024);
  }

  // ---- A prologue: thread (arow = tid>>3, aj = tid&7) stages row arow's
  // floats [kc*32 + aj*4 .. +3] for all kc; XOR-swizzled 16B chunks ----
  const int arow = tid >> 3;
  const int aj = tid & 7;
  const float* aSrc = feat + (size_t)(r0 + arow) * DD + aj * 4;
  const int awbase =
      arow * 64 + (((aj >> 1) ^ ((arow >> 1) & 3)) * 16) + (aj & 1) * 8;

  float s = 0.f;
  {
    f32x4 av0[8], av1[8];
#pragma unroll
    for (int i = 0; i < 8; ++i) av0[i] = *(const f32x4*)(aSrc + i * 32);
#pragma unroll
    for (int i = 0; i < 8; ++i) av1[i] = *(const f32x4*)(aSrc + (8 + i) * 32);
#pragma unroll
    for (int i = 0; i < 8; ++i) {
      f16x4 h;
#pragma unroll
      for (int u = 0; u < 4; ++u) {
        h[u] = (_Float16)av0[i][u];
        s = fmaf(av0[i][u], av0[i][u], s);
      }
      *(f16x4*)(&Afull[i * 4096 + awbase]) = h;
    }
#pragma unroll
    for (int i = 0; i < 8; ++i) {
      f16x4 h;
#pragma unroll
      for (int u = 0; u < 4; ++u) {
        h[u] = (_Float16)av1[i][u];
        s = fmaf(av1[i][u], av1[i][u], s);
      }
      *(f16x4*)(&Afull[(8 + i) * 4096 + awbase]) = h;
    }
  }
  // f2 for row arow: 8 consecutive lanes (aj 0..7) share it
  s += __shfl_xor(s, 1, 64);
  s += __shfl_xor(s, 2, 64);
  s += __shfl_xor(s, 4, 64);
  if ((lane & 7) == 0) f2l[arow] = s;

  p2l[tid] = p2[tid];
  if (tid < 64) labl[tid] = labels[r0 + tid];

  f32x4 acc[4][4];
#pragma unroll
  for (int mt = 0; mt < 4; ++mt)
#pragma unroll
    for (int nt = 0; nt < 4; ++nt) acc[mt][nt] = (f32x4){0.f, 0.f, 0.f, 0.f};

  __syncthreads();  // barrier #1: A tile + scalars staged

  // ---- K-loop: NO barriers, no LDS writes, no HBM; rotated A pages + B
  // units (kr), ring-3/depth-2 B prefetch ----
  const int aroff = lane16 * 64 + ((quad ^ ((lane16 >> 1) & 3)) * 16);
#pragma unroll
  for (int kc = 0; kc < NK; ++kc) {
    const int kr = (kc + rot) & 15;
    if (kc + 2 < NK) {
      const int kp = (kc + 2 + rot) & 15;
#pragma unroll
      for (int nt = 0; nt < 4; ++nt)
        bfr[(kc + 2) % 3][nt] = *(const f16x8*)(bptr[nt] + (size_t)kp * 1024);
    }
    f16x8 af[4];
#pragma unroll
    for (int mt = 0; mt < 4; ++mt)
      af[mt] = *(const f16x8*)(&Afull[kr * 4096 + mt * 1024 + aroff]);
#pragma unroll
    for (int mt = 0; mt < 4; ++mt)
#pragma unroll
      for (int nt = 0; nt < 4; ++nt)
        acc[mt][nt] = __builtin_amdgcn_mfma_f32_16x16x32_f16(
            af[mt], bfr[kc % 3][nt], acc[mt][nt], 0, 0, 0);
  }

  // ---- epilogue: q = p2 - 2*dot; masked min/pos over my 64 cols ----
  float p2v[4];
#pragma unroll
  for (int nt = 0; nt < 4; ++nt) p2v[nt] = p2l[w * 64 + nt * 16 + lane16];

#pragma unroll
  for (int mt = 0; mt < 4; ++mt) {
#pragma unroll
    for (int i = 0; i < 4; ++i) {
      const int row = mt * 16 + quad * 4 + i;
      const int lb = labl[row];
      float qm = 1e30f, qp = -1e30f;
#pragma unroll
      for (int nt = 0; nt < 4; ++nt) {
        const int col = w * 64 + nt * 16 + lane16;
        float q = p2v[nt] - 2.f * acc[mt][nt][i];
        bool isPos = (col == lb);
        qp = fmaxf(qp, isPos ? q : -1e30f);
        qm = fminf(qm, (!isPos && col < CC) ? q : 1e30f);
      }
#pragma unroll
      for (int d = 1; d < 16; d <<= 1) {
        qm = fminf(qm, __shfl_xor(qm, d, 64));
        qp = fmaxf(qp, __shfl_xor(qp, d, 64));
      }
      if (lane16 == 0) {
        redM[row * 8 + w] = qm;
        redP[row * 8 + w] = qp;
      }
    }
  }
  __syncthreads();  // barrier #2: partials visible

  // ---- combine 8 octants per row, sqrt+hinge, block sum, one atomic ----
  if (tid < 64) {
    float qm = 1e30f, qp = -1e30f;
#pragma unroll
    for (int j = 0; j < 8; ++j) {
      qm = fminf(qm, redM[tid * 8 + j]);
      qp = fmaxf(qp, redP[tid * 8 + j]);
    }
    float f2 = f2l[tid];
    float dn = sqrtf(fmaxf(f2 + qm, EPSQ));
    float dp = sqrtf(fmaxf(f2 + qp, EPSQ));
    float term = fmaxf(dp - dn + LMARGIN, 0.f);
#pragma unroll
    for (int d = 1; d < 64; d <<= 1) term += __shfl_xor(term, d, 64);
    if (tid == 0) atomicAdd(out, term * (1.0f / BB));
  }
}

extern "C" void kernel_launch(void* const* d_in, const int* in_sizes, int n_in,
                              void* d_out, int out_size, void* d_ws, size_t ws_size,
                              hipStream_t stream) {
  const float* feat = (const float*)d_in[0];
  const float* protos = (const float*)d_in[1];
  const int* labels = (const int*)d_in[2];
  float* out = (float*)d_out;

  char* ws = (char*)d_ws;
  unsigned short* protoT = (unsigned short*)(ws);   // 512 KB fragment-linear B
  float* p2 = (float*)(ws + (512 << 10));           // 2 KB

  prepP_kernel<<<32, 256, 0, stream>>>(protos, protoT, p2, out);
  main_kernel<<<BB / 64, 512, 0, stream>>>(feat, protoT, p2, labels, out);
}